// Round 1
// baseline (324.477 us; speedup 1.0000x reference)
//
#include <hip/hip_runtime.h>

// Unfold (im2col): x[8,64,224,224] f32, 3x3 kernel, pad=1, stride=1, dil=1
// out[b, c*9 + k, oh*224 + ow] = x[b, c, oh+ki-1, ow+kj-1] (0 outside), k = ki*3+kj

constexpr int B = 8, C = 64, H = 224, W = 224;
constexpr int L  = H * W;        // 50176
constexpr int L4 = L / 4;        // 12544 (W % 4 == 0, so a float4 never crosses a row)
constexpr int ROWS = B * C * 9;  // 4608
constexpr unsigned TOTAL4 = (unsigned)ROWS * (unsigned)L4;  // 57,802,752 < 2^31

__global__ __launch_bounds__(256) void unfold_kernel(const float* __restrict__ x,
                                                     float* __restrict__ out) {
    unsigned idx = blockIdx.x * 256u + threadIdx.x;
    if (idx >= TOTAL4) return;

    // Decompose: idx = row * L4 + l4, row = (b*C + c)*9 + k
    unsigned l4  = idx % L4;          // const-divisor -> magic mul
    unsigned row = idx / L4;
    unsigned k   = row % 9u;
    unsigned cc  = row / 9u;          // b*C + c  (combined: x is contiguous in (b,c))
    int ki = (int)(k / 3u);
    int kj = (int)(k % 3u);

    int l  = (int)(l4 * 4u);
    int oh = l / W;
    int ow = l - oh * W;

    int ih = oh + ki - 1;

    float4 v = make_float4(0.f, 0.f, 0.f, 0.f);
    if (ih >= 0 && ih < H) {
        const float* __restrict__ src = x + ((size_t)cc * H + (size_t)ih) * W;
        int iw = ow + kj - 1;
        float* pv = &v.x;
        #pragma unroll
        for (int j = 0; j < 4; ++j) {
            int w = iw + j;
            if (w >= 0 && w < W) pv[j] = src[w];
        }
    }
    reinterpret_cast<float4*>(out)[idx] = v;
}

extern "C" void kernel_launch(void* const* d_in, const int* in_sizes, int n_in,
                              void* d_out, int out_size, void* d_ws, size_t ws_size,
                              hipStream_t stream) {
    const float* x = (const float*)d_in[0];
    float* out = (float*)d_out;
    unsigned blocks = (TOTAL4 + 255u) / 256u;  // 225,792
    unfold_kernel<<<dim3(blocks), dim3(256), 0, stream>>>(x, out);
}

// Round 2
// 211.849 us; speedup vs baseline: 1.5316x; 1.5316x over previous
//
#include <hip/hip_runtime.h>

// Unfold (im2col): x[8,64,224,224] f32, 3x3 kernel, pad=1, stride=1, dil=1
// out[b, c*9 + k, oh*224 + ow] = x[b, c, oh+ki-1, ow+kj-1] (0 outside), k = ki*3+kj
// One thread per (b*c, output-quad): loads 3 rows (1 aligned float4 + 2 edge
// scalars each), composes the 3 kj-shifts in-register, stores 9 float4s.

constexpr int B = 8, C = 64, H = 224, W = 224;
constexpr int L  = H * W;          // 50176
constexpr int L4 = L / 4;          // 12544 (W % 4 == 0: quads never cross rows)
constexpr int CC = B * C;          // 512
constexpr unsigned TOTALT = (unsigned)CC * (unsigned)L4;  // 6,422,528 threads

__global__ __launch_bounds__(256) void unfold9_kernel(const float* __restrict__ x,
                                                      float* __restrict__ out) {
    unsigned t = blockIdx.x * 256u + threadIdx.x;
    if (t >= TOTALT) return;

    unsigned l4 = t % (unsigned)L4;   // const-divisor -> magic mul
    unsigned cc = t / (unsigned)L4;
    int l  = (int)(l4 * 4u);
    int oh = l / W;
    int ow = l - oh * W;              // aligned quad start, 0..220

    const float* __restrict__ base = x + (size_t)cc * (size_t)L;

    float4 row[3];
    float  lft[3], rgt[3];
    #pragma unroll
    for (int ki = 0; ki < 3; ++ki) {
        int ih = oh + ki - 1;
        if (ih >= 0 && ih < H) {
            const float* __restrict__ src = base + ih * W;
            row[ki] = *reinterpret_cast<const float4*>(src + ow);  // aligned
            lft[ki] = (ow > 0)     ? src[ow - 1] : 0.f;
            rgt[ki] = (ow < W - 4) ? src[ow + 4] : 0.f;
        } else {
            row[ki] = make_float4(0.f, 0.f, 0.f, 0.f);
            lft[ki] = 0.f;
            rgt[ki] = 0.f;
        }
    }

    float4* __restrict__ o = reinterpret_cast<float4*>(out);
    size_t obase = (size_t)cc * 9u * (size_t)L4 + (size_t)l4;
    #pragma unroll
    for (int ki = 0; ki < 3; ++ki) {
        float4 q = row[ki];
        float4 a = make_float4(lft[ki], q.x, q.y, q.z);   // kj = 0 (shift left)
        float4 c = make_float4(q.y, q.z, q.w, rgt[ki]);   // kj = 2 (shift right)
        o[obase + (size_t)(ki * 3 + 0) * (size_t)L4] = a;
        o[obase + (size_t)(ki * 3 + 1) * (size_t)L4] = q;
        o[obase + (size_t)(ki * 3 + 2) * (size_t)L4] = c;
    }
}

extern "C" void kernel_launch(void* const* d_in, const int* in_sizes, int n_in,
                              void* d_out, int out_size, void* d_ws, size_t ws_size,
                              hipStream_t stream) {
    const float* x = (const float*)d_in[0];
    float* out = (float*)d_out;
    unsigned blocks = (TOTALT + 255u) / 256u;  // 25,088
    unfold9_kernel<<<dim3(blocks), dim3(256), 0, stream>>>(x, out);
}